// Round 5
// baseline (504.625 us; speedup 1.0000x reference)
//
#include <hip/hip_runtime.h>
#include <hip/hip_bf16.h>
#include <cstddef>
#include <cstdint>

typedef __bf16 bf16;
typedef __bf16 bf16x4 __attribute__((ext_vector_type(4)));
typedef __bf16 bf16x8 __attribute__((ext_vector_type(8)));
typedef float f32x4 __attribute__((ext_vector_type(4)));
typedef float f32x16 __attribute__((ext_vector_type(16)));
typedef unsigned int u32x4 __attribute__((ext_vector_type(4)));

#define GLD_LDS16(g, l) __builtin_amdgcn_global_load_lds( \
    (const __attribute__((address_space(1))) void*)(g),   \
    (__attribute__((address_space(3))) void*)(l), 16, 0, 0)

#define SBAR __builtin_amdgcn_s_barrier()
#define SCHED0 __builtin_amdgcn_sched_barrier(0)
#define VMW(n) asm volatile("s_waitcnt vmcnt(" #n ")" ::: "memory")

// pack two f32 -> one u32 of 2 bf16 (elem0 = lo, elem1 = hi)
static __device__ inline unsigned int cvtpk(float lo, float hi) {
  unsigned int r;
  asm("v_cvt_pk_bf16_f32 %0, %1, %2" : "=v"(r) : "v"(lo), "v"(hi));
  return r;
}
// v_permlane32_swap_b32: a.hi32lanes <-> b.lo32lanes
static __device__ inline void plswap(unsigned int& a, unsigned int& b) {
  asm("v_permlane32_swap_b32 %0, %1" : "+v"(a), "+v"(b));
}
// raw hardware exp2 (inputs bounded; no denormal guard needed)
static __device__ inline float fexp2(float x) {
#if __has_builtin(__builtin_amdgcn_exp2f)
  return __builtin_amdgcn_exp2f(x);
#else
  float r; asm("v_exp_f32 %0, %1" : "=v"(r) : "v"(x)); return r;
#endif
}
// pairwise tree sum of 16 floats (depth 4, no serial chain)
static __device__ inline float tsum16(const float* e) {
  float s0 = e[0] + e[1], s1 = e[2] + e[3], s2 = e[4] + e[5], s3 = e[6] + e[7];
  float s4 = e[8] + e[9], s5 = e[10] + e[11], s6 = e[12] + e[13], s7 = e[14] + e[15];
  return ((s0 + s1) + (s2 + s3)) + ((s4 + s5) + (s6 + s7));
}

// ---------------- src cast: f32 -> bf16, 8 elems/thread ----------------
__global__ void __launch_bounds__(256)
k_cast(const float* __restrict__ in, bf16* __restrict__ out) {
  int gid = blockIdx.x * 256 + threadIdx.x;
  f32x4 a = ((const f32x4*)in)[gid * 2];
  f32x4 b = ((const f32x4*)in)[gid * 2 + 1];
  bf16x8 o;
#pragma unroll
  for (int i = 0; i < 4; ++i) { o[i] = (bf16)a[i]; o[i + 4] = (bf16)b[i]; }
  ((bf16x8*)out)[gid] = o;
}

// ---- tiled transpose: in f32 (R x C) -> out bf16 (C x R), 64x64 tiles ----
__global__ void __launch_bounds__(256)
k_transpose_t(const float* __restrict__ in, bf16* __restrict__ out, int R, int C) {
  __shared__ float tile[64][68];
  const int nct = C >> 6;
  const int bc = blockIdx.x % nct, br = blockIdx.x / nct;
  const int r0 = br << 6, c0 = bc << 6;
  const int t = threadIdx.x;
  const int tr = t >> 4, tc4 = (t & 15) << 2;
#pragma unroll
  for (int i = 0; i < 4; ++i)
    *(f32x4*)&tile[i * 16 + tr][tc4] =
        *(const f32x4*)&in[(size_t)(r0 + i * 16 + tr) * C + c0 + tc4];
  __syncthreads();
  const int c = t >> 2, rch = (t & 3) << 4;
  bf16 ob[16];
#pragma unroll
  for (int j = 0; j < 16; ++j) ob[j] = (bf16)tile[rch + j][c];
  bf16* dst = out + (size_t)(c0 + c) * R + r0 + rch;
  *(bf16x8*)&dst[0] = *(bf16x8*)&ob[0];
  *(bf16x8*)&dst[8] = *(bf16x8*)&ob[8];
}

// ---- QKV weight repack (tiled): W (H,D,DK) f32 -> WqkvT[(proj*1024+h*64+dk)][d] bf16 ----
__global__ void __launch_bounds__(256)
k_reorder_qkv_t(const float* __restrict__ Wq, const float* __restrict__ Wk,
                const float* __restrict__ Wv, bf16* __restrict__ WqkvT) {
  __shared__ float tile[64][68];
  const int bid = blockIdx.x;
  const int sub = bid >> 4, tl = bid & 15;
  const int proj = sub >> 4, h = sub & 15;
  const float* W = (proj == 0) ? Wq : (proj == 1) ? Wk : Wv;
  const float* src = W + (size_t)h * 65536;   // (1024 d x 64 dk)
  const int r0 = tl << 6;
  const int t = threadIdx.x, tr = t >> 4, tc4 = (t & 15) << 2;
#pragma unroll
  for (int i = 0; i < 4; ++i)
    *(f32x4*)&tile[i * 16 + tr][tc4] =
        *(const f32x4*)&src[(size_t)(r0 + i * 16 + tr) * 64 + tc4];
  __syncthreads();
  const int c = t >> 2, rch = (t & 3) << 4;   // c = dk
  bf16 ob[16];
#pragma unroll
  for (int j = 0; j < 16; ++j) ob[j] = (bf16)tile[rch + j][c];
  bf16* dst = WqkvT + ((size_t)(proj * 1024 + h * 64 + c)) * 1024 + r0 + rch;
  *(bf16x8*)&dst[0] = *(bf16x8*)&ob[0];
  *(bf16x8*)&dst[8] = *(bf16x8*)&ob[8];
}

__global__ void __launch_bounds__(256)
k_bias_qkv(const float* __restrict__ bq, const float* __restrict__ bk,
           const float* __restrict__ bv, float* __restrict__ bqkv) {
  int n = blockIdx.x * 256 + threadIdx.x;   // 3072
  int proj = n >> 10, wi = n & 1023;
  const float* bb = (proj == 0) ? bq : (proj == 1) ? bk : bv;
  bqkv[n] = bb[wi];
}

// ======== k_gemmS: 128x256 tile, square 64x64 waves (LDS-read-minimal) ========
// 512 thr / 8 waves (2M x 4N), per-wave 64x64 -> reads (64+64)*64*2 = 16KB/wave/tile
// vs 20KB for 128x32 waves. 3-slot LDS ring (48KB/tile), stage-2-ahead,
// single counted VMW(12) + 2 barriers per K-tile. T2 involution swizzle.
template <int MODE>
__global__ void __launch_bounds__(512, 1)
k_gemmS(const bf16* __restrict__ A, const bf16* __restrict__ Bt,
        const float* __restrict__ bias, void* __restrict__ outp,
        int M, int N, int K,
        bf16* __restrict__ qb, bf16* __restrict__ kb, bf16* __restrict__ vb) {
  __shared__ __align__(16) bf16 Asl[3][8192];    // [128 rows][64 k]
  __shared__ __align__(16) bf16 Bsl[3][16384];   // [256 rows][64 k]

  const int tid = threadIdx.x;
  const int lane = tid & 63, wave = tid >> 6;
  const int l16 = lane & 15, lq = lane >> 4;
  const int qwm = wave >> 2, qwn = wave & 3;

  const int mtiles = M >> 7;
  const int wg = blockIdx.x;                 // linear: tile_m fastest (L2/L3 reuse)
  const int tile_m = (wg % mtiles) << 7;
  const int tile_n = (wg / mtiles) << 8;

  const bf16* Abase = A + (size_t)tile_m * K;
  const bf16* Bbase = Bt + (size_t)tile_n * K;

  // staging: chunk c -> row c>>3, pos-col c&7; source col = pos ^ (row&7)
  const int crow = tid >> 3;
  const int ccol = ((tid & 7) ^ (crow & 7)) << 3;

  auto STAGE = [&](int T, int slot) {
    const bf16* a_ = Abase + (size_t)crow * K + T * 64 + ccol;
    GLD_LDS16(a_, &Asl[slot][tid * 8]);
    GLD_LDS16(a_ + (size_t)64 * K, &Asl[slot][tid * 8 + 4096]);
    const bf16* b_ = Bbase + (size_t)crow * K + T * 64 + ccol;
    GLD_LDS16(b_, &Bsl[slot][tid * 8]);
    GLD_LDS16(b_ + (size_t)64 * K, &Bsl[slot][tid * 8 + 4096]);
    GLD_LDS16(b_ + (size_t)128 * K, &Bsl[slot][tid * 8 + 8192]);
    GLD_LDS16(b_ + (size_t)192 * K, &Bsl[slot][tid * 8 + 12288]);
  };

  // ds_read: row swizzle key = l16&7 (all frag rows are +16 multiples)
  const int xk = l16 & 7;
  const int swz0 = (lq ^ xk) * 16;
  const int swz1 = ((4 | lq) ^ xk) * 16;
  const int arow_b = (qwm * 64 + l16) * 128;
  const int brow_b = (qwn * 64 + l16) * 128;

  f32x4 acc[4][4] = {};

  const int NT = K >> 6;
  STAGE(0, 0); STAGE(1, 1);

  for (int t = 0; t < NT; ++t) {
    const int slot = t % 3;
    if (t + 2 < NT) STAGE(t + 2, (t + 2) % 3);   // writes slot (t-1): safe post-barrier
    SCHED0;
    if (t + 2 < NT) { VMW(12); }
    else if (t + 1 < NT) { VMW(6); }
    else { VMW(0); }
    SBAR;
    SCHED0;

    const char* Ab = (const char*)&Asl[slot][0] + arow_b;
    const char* Bb = (const char*)&Bsl[slot][0] + brow_b;
    bf16x8 af[4][2], bfr[4][2];
#pragma unroll
    for (int mi = 0; mi < 4; ++mi) {
      af[mi][0] = *(const bf16x8*)(Ab + mi * 2048 + swz0);
      af[mi][1] = *(const bf16x8*)(Ab + mi * 2048 + swz1);
    }
#pragma unroll
    for (int ni = 0; ni < 2; ++ni) {
      bfr[ni][0] = *(const bf16x8*)(Bb + ni * 2048 + swz0);
      bfr[ni][1] = *(const bf16x8*)(Bb + ni * 2048 + swz1);
    }
    __builtin_amdgcn_s_setprio(1);
#pragma unroll
    for (int mi = 0; mi < 4; ++mi)
#pragma unroll
      for (int ni = 0; ni < 2; ++ni)
#pragma unroll
        for (int p = 0; p < 2; ++p)
          acc[mi][ni] = __builtin_amdgcn_mfma_f32_16x16x32_bf16(
              af[mi][p], bfr[ni][p], acc[mi][ni], 0, 0, 0);
    __builtin_amdgcn_s_setprio(0);
#pragma unroll
    for (int ni = 2; ni < 4; ++ni) {
      bfr[ni][0] = *(const bf16x8*)(Bb + ni * 2048 + swz0);
      bfr[ni][1] = *(const bf16x8*)(Bb + ni * 2048 + swz1);
    }
    __builtin_amdgcn_s_setprio(1);
#pragma unroll
    for (int mi = 0; mi < 4; ++mi)
#pragma unroll
      for (int ni = 2; ni < 4; ++ni)
#pragma unroll
        for (int p = 0; p < 2; ++p)
          acc[mi][ni] = __builtin_amdgcn_mfma_f32_16x16x32_bf16(
              af[mi][p], bfr[ni][p], acc[mi][ni], 0, 0, 0);
    __builtin_amdgcn_s_setprio(0);
    SBAR;                                    // all reads of slot t done
  }

  // ---------------- epilogue ----------------
#pragma unroll
  for (int mi = 0; mi < 4; ++mi)
#pragma unroll
    for (int ni = 0; ni < 4; ++ni) {
      const int gn = tile_n + qwn * 64 + ni * 16 + l16;
      const float bv = bias[gn];
      f32x4 v = acc[mi][ni];
      const int gm0 = tile_m + qwm * 64 + mi * 16 + lq * 4;
      if (MODE == 0) {
        int proj = gn >> 10, wi = gn & 1023;
        int h = wi >> 6, dk = wi & 63;
        int b = gm0 >> 11, sdx = gm0 & 2047;
        size_t bhs = (size_t)((b << 4) + h);
        if (proj == 0) {
#pragma unroll
          for (int i2 = 0; i2 < 4; ++i2)
            qb[(bhs * 2048 + sdx + i2) * 64 + dk] = (bf16)((v[i2] + bv) * 0.18033688f);
        } else if (proj == 1) {
#pragma unroll
          for (int i2 = 0; i2 < 4; ++i2)
            kb[(bhs * 2048 + sdx + i2) * 64 + dk] = (bf16)(v[i2] + bv);
        } else {
          bf16x4 pk;
#pragma unroll
          for (int i2 = 0; i2 < 4; ++i2) pk[i2] = (bf16)(v[i2] + bv);
          *(bf16x4*)&vb[(bhs * 64 + dk) * 2048 + sdx] = pk;   // V^T
        }
      } else if (MODE == 1) {
#pragma unroll
        for (int i2 = 0; i2 < 4; ++i2)
          ((bf16*)outp)[(size_t)(gm0 + i2) * N + gn] = (bf16)(v[i2] + bv);
      } else {
#pragma unroll
        for (int i2 = 0; i2 < 4; ++i2)
          ((bf16*)outp)[(size_t)(gm0 + i2) * N + gn] = (bf16)fmaxf(v[i2] + bv, 0.f);
      }
    }
}

// ======== 4-fat-phase 256x256 GEMM (NREP=2 only; used for FF1) ========
template <int MODE, int NREP>
__global__ void __launch_bounds__(512, 1)
k_gemm4(const bf16* __restrict__ A, const bf16* __restrict__ Bt,
        const float* __restrict__ bias, void* __restrict__ outp,
        int M, int N, int K,
        bf16* __restrict__ qb, bf16* __restrict__ kb, bf16* __restrict__ vb) {
  constexpr int BN = 128 * NREP;
  constexpr int BROWS = 64 * NREP;          // rows per B half-slot
  __shared__ __align__(16) bf16 Asl[4][8192];          // 4 x (128 x 64)
  __shared__ __align__(16) bf16 Bsl[4][BROWS * 64];    // 4 x (BROWS x 64)

  const int tid = threadIdx.x;
  const int lane = tid & 63, wave = tid >> 6;
  const int l16 = lane & 15, lq = lane >> 4;
  const int qwm = wave >> 2, qwn = wave & 3;

  const int mtiles = M >> 8;
  const int wg = blockIdx.x;                 // linear: tile_m fastest
  const int tile_m = (wg % mtiles) << 8;
  const int tile_n = (wg / mtiles) * BN;

  const bf16* Abase = A + (size_t)tile_m * K;
  const bf16* Bbase = Bt + (size_t)tile_n * K;

  const int crow = tid >> 3;
  const int ccol = ((tid & 7) ^ (crow & 7)) << 3;

  auto stageA = [&](int T, int h, int slot) {
    const bf16* s_ = Abase + (size_t)(h * 128 + crow) * K + T * 64 + ccol;
    GLD_LDS16(s_, &Asl[slot][tid * 8]);
    GLD_LDS16(s_ + (size_t)64 * K, &Asl[slot][tid * 8 + 4096]);
  };
  auto stageB = [&](int T, int h, int slot) {
    const bf16* s_ = Bbase + (size_t)(h * BROWS + crow) * K + T * 64 + ccol;
    GLD_LDS16(s_, &Bsl[slot][tid * 8]);
    if (NREP == 2) GLD_LDS16(s_ + (size_t)64 * K, &Bsl[slot][tid * 8 + 4096]);
  };

  const int xk = l16 & 7;
  const int swz0 = (lq ^ xk) * 16;
  const int swz1 = ((4 | lq) ^ xk) * 16;
  const int arow_b = (qwm * 64 + l16) * 128;
  const int brow_b = (qwn * 16 * NREP + l16) * 128;

  bf16x8 af[4][2];
  bf16x8 bb[2][NREP][2];
  f32x4 acc[2][2][4][NREP] = {};

  auto dsA = [&](int slot) {
    const char* Ab = (const char*)&Asl[slot][0] + arow_b;
#pragma unroll
    for (int mi = 0; mi < 4; ++mi) {
      af[mi][0] = *(const bf16x8*)(Ab + mi * 2048 + swz0);
      af[mi][1] = *(const bf16x8*)(Ab + mi * 2048 + swz1);
    }
  };
  auto dsB2 = [&](int slot0, int slot1) {
    const char* B0 = (const char*)&Bsl[slot0][0] + brow_b;
    const char* B1 = (const char*)&Bsl[slot1][0] + brow_b;
#pragma unroll
    for (int ni = 0; ni < NREP; ++ni) {
      bb[0][ni][0] = *(const bf16x8*)(B0 + ni * 2048 + swz0);
      bb[0][ni][1] = *(const bf16x8*)(B0 + ni * 2048 + swz1);
      bb[1][ni][0] = *(const bf16x8*)(B1 + ni * 2048 + swz0);
      bb[1][ni][1] = *(const bf16x8*)(B1 + ni * 2048 + swz1);
    }
  };
  auto MF2 = [&](int mh) {
    __builtin_amdgcn_s_setprio(1);
#pragma unroll
    for (int nh = 0; nh < 2; ++nh)
#pragma unroll
      for (int mi = 0; mi < 4; ++mi)
#pragma unroll
        for (int ni = 0; ni < NREP; ++ni)
#pragma unroll
          for (int p = 0; p < 2; ++p)
            acc[mh][nh][mi][ni] = __builtin_amdgcn_mfma_f32_16x16x32_bf16(
                af[mi][p], bb[nh][ni][p], acc[mh][nh][mi][ni], 0, 0, 0);
    __builtin_amdgcn_s_setprio(0);
  };

  const int NT = K >> 6;
  const int NI = NT >> 1;

  stageA(0, 0, 0); stageA(0, 1, 1); stageB(0, 0, 0); stageB(0, 1, 1);
  stageA(1, 0, 2); stageB(1, 0, 2); stageB(1, 1, 3);
  SCHED0;
  if (NREP == 2) { VMW(6); } else { VMW(4); }
  SBAR;

  for (int i = 0; i < NI; ++i) {
    const int t2 = 2 * i + 2, t3 = 2 * i + 3;
    const bool tv = (t2 < NT);
    dsA(0); dsB2(0, 1);
    stageA(2 * i + 1, 1, 3);
    SCHED0;
    if (NREP == 2) { VMW(10); } else { VMW(7); }
    SBAR; MF2(0); SBAR;
    dsA(1);
    if (tv) { stageA(t2, 0, 0); stageB(t2, 0, 0); }
    SCHED0;
    if (!tv) { VMW(2); }
    else if (NREP == 2) { VMW(6); } else { VMW(5); }
    SBAR; MF2(1); SBAR;
    dsA(2); dsB2(2, 3);
    if (tv) { stageA(t2, 1, 1); stageB(t2, 1, 1); }
    SCHED0;
    if (!tv) { VMW(0); }
    else if (NREP == 2) { VMW(8); } else { VMW(6); }
    SBAR; MF2(0); SBAR;
    dsA(3);
    if (tv) {
      stageA(t3, 0, 2); stageB(t3, 0, 2); stageB(t3, 1, 3);
      SCHED0;
      if (NREP == 2) { VMW(6); } else { VMW(4); }
    }
    SBAR; MF2(1); SBAR;
  }

#pragma unroll
  for (int mh = 0; mh < 2; ++mh)
#pragma unroll
    for (int nh = 0; nh < 2; ++nh)
#pragma unroll
      for (int mi = 0; mi < 4; ++mi)
#pragma unroll
        for (int ni = 0; ni < NREP; ++ni) {
          const int gn = tile_n + nh * (BN / 2) + qwn * 16 * NREP + ni * 16 + l16;
          const float bv = bias[gn];
          f32x4 v = acc[mh][nh][mi][ni];
          const int gm0 = tile_m + mh * 128 + qwm * 64 + mi * 16 + lq * 4;
          if (MODE == 1) {
#pragma unroll
            for (int i2 = 0; i2 < 4; ++i2)
              ((bf16*)outp)[(size_t)(gm0 + i2) * N + gn] = (bf16)(v[i2] + bv);
          } else {
#pragma unroll
            for (int i2 = 0; i2 < 4; ++i2)
              ((bf16*)outp)[(size_t)(gm0 + i2) * N + gn] = (bf16)fmaxf(v[i2] + bv, 0.f);
          }
        }
}

// ---- flash attention, 32x32 MFMA, triple-buffered counted-vmcnt pipeline ----
__global__ void __launch_bounds__(256, 2)
k_attn(const bf16* __restrict__ qb, const bf16* __restrict__ kb,
       const bf16* __restrict__ vb, bf16* __restrict__ ctx) {
  __shared__ __align__(16) bf16 KsL[3][4096];   // [64 s][64 d], swizzled chunks
  __shared__ __align__(16) bf16 VsL[3][4096];   // [64 d][64 s], swizzled chunks

  const int bid = blockIdx.x;
  const int wg = (bid & 7) * 64 + (bid >> 3);
  const int bh = wg >> 3, qt = wg & 7;

  const bf16* Qp  = qb + (size_t)bh * 131072 + (size_t)qt * 16384;
  const bf16* Kbh = kb + (size_t)bh * 131072;
  const bf16* Vbh = vb + (size_t)bh * 131072;

  const int tid = threadIdx.x, wave = tid >> 6, lane = tid & 63;
  const int l31 = lane & 31, hi = lane >> 5;

  bf16x8 qfA[4], qfB[4];
  {
    const bf16* qra = Qp + (size_t)(wave * 64 + l31) * 64 + hi * 8;
    const bf16* qrb = qra + 32 * 64;
#pragma unroll
    for (int kd = 0; kd < 4; ++kd) {
      qfA[kd] = *(const bf16x8*)(qra + kd * 16);
      qfB[kd] = *(const bf16x8*)(qrb + kd * 16);
    }
  }

  const int c0 = tid, c1 = tid + 256;
  const int sw0 = ((c0 ^ (c0 >> 3)) & 7) * 8, rw0 = c0 >> 3;
  const int sw1 = ((c1 ^ (c1 >> 3)) & 7) * 8, rw1 = c1 >> 3;
  const int kof0 = rw0 * 64 + sw0, kof1 = rw1 * 64 + sw1;
  const int vof0 = rw0 * 2048 + sw0, vof1 = rw1 * 2048 + sw1;

  const int xr = (hi << 4) ^ ((l31 & 7) << 4);
  const int rb = l31 * 128 + xr;

  f32x16 oA[2] = {}, oB[2] = {};
  float lA = 0.f, lB = 0.f;

#define STAGE_KV(buf, s0)                                             \
  do {                                                                \
    GLD_LDS16(Kbh + (size_t)(s0) * 64 + kof0, &KsL[buf][c0 * 8]);     \
    GLD_LDS16(Kbh + (size_t)(s0) * 64 + kof1, &KsL[buf][c1 * 8]);     \
    GLD_LDS16(Vbh + (s0) + vof0, &VsL[buf][c0 * 8]);                  \
    GLD_LDS16(Vbh + (s0) + vof1, &VsL[buf][c1 * 8]);                  \
  } while (0)

  STAGE_KV(0, 0);
  STAGE_KV(1, 64);

  int cur = 0;
  for (int kt = 0; kt < 32; ++kt) {
    SCHED0;
    if (kt == 31) { VMW(0); }
    else          { VMW(4); }
    __builtin_amdgcn_s_barrier();
    SCHED0;

    if (kt < 30) {
      int nx = cur + 2; if (nx >= 3) nx -= 3;
      STAGE_KV(nx, (kt + 2) * 64);
    }

    const char* Kc = (const char*)&KsL[cur][0];
    const char* Vc = (const char*)&VsL[cur][0];

    bf16x8 paA[4], paB[4];
#pragma unroll
    for (int st = 0; st < 2; ++st) {
      f32x16 sA = {}, sB = {};
      __builtin_amdgcn_s_setprio(1);
#pragma unroll
      for (int kd = 0; kd < 4; ++kd) {
        bf16x8 a = *(const bf16x8*)(Kc + st * 4096 + (rb ^ (kd << 5)));
        sA = __builtin_amdgcn_mfma_f32_32x32x16_bf16(a, qfA[kd], sA, 0, 0, 0);
        sB = __builtin_amdgcn_mfma_f32_32x32x16_bf16(a, qfB[kd], sB, 0, 0, 0);
      }
      __builtin_amdgcn_s_setprio(0);

      float eA[16], eB[16];
#pragma unroll
      for (int i = 0; i < 16; ++i) {
        eA[i] = fexp2(sA[i]);
        eB[i] = fexp2(sB[i]);
      }
      lA += tsum16(eA);
      lB += tsum16(eB);
      unsigned int qdA[4][2], qdB[4][2];
#pragma unroll
      for (int g = 0; g < 4; ++g)
#pragma unroll
        for (int w = 0; w < 2; ++w) {
          qdA[g][w] = cvtpk(eA[g * 4 + w * 2], eA[g * 4 + w * 2 + 1]);
          qdB[g][w] = cvtpk(eB[g * 4 + w * 2], eB[g * 4 + w * 2 + 1]);
        }
#pragma unroll
      for (int a2 = 0; a2 < 2; ++a2) {
        unsigned int x0 = qdA[2 * a2][0], y0 = qdA[2 * a2 + 1][0];
        unsigned int x1 = qdA[2 * a2][1], y1 = qdA[2 * a2 + 1][1];
        plswap(x0, y0); plswap(x1, y1);
        u32x4 fA = {x0, x1, y0, y1};
        paA[st * 2 + a2] = __builtin_bit_cast(bf16x8, fA);
        unsigned int u0 = qdB[2 * a2][0], v0 = qdB[2 * a2 + 1][0];
        unsigned int u1 = qdB[2 * a2][1], v1 = qdB[2 * a2 + 1][1];
        plswap(u0, v0); plswap(u1, v1);
        u32x4 fB = {u0, u1, v0, v1};
        paB[st * 2 + a2] = __builtin_bit_cast(bf16x8, fB);
      }
    }

    __builtin_amdgcn_s_setprio(1);
#pragma unroll
    for (int nd = 0; nd < 2; ++nd)
#pragma unroll
      for (int ks = 0; ks < 4; ++ks) {
        bf16x8 vf = *(const bf16x8*)(Vc + nd * 4096 + (rb ^ (ks << 5)));
        oA[nd] = __builtin_amdgcn_mfma_f32_32x32x16_bf16(paA[ks], vf, oA[nd], 0, 0, 0);
        oB[nd] = __builtin_amdgcn_mfma_f32_32x32x16_bf16(paB[ks], vf, oB[nd], 0, 0, 0);
      }
    __builtin_amdgcn_s_setprio(0);

    if (++cur == 3) cur = 0;
  }
#undef STAGE_KV

  const float ltA = lA + __shfl_xor(lA, 32);
  const float ltB = lB + __shfl_xor(lB, 32);
  const float ivA = 1.f / ltA;
  const float ivB = 1.f / ltB;

  const int b = bh >> 4, h = bh & 15;
  const size_t rowbase = (size_t)(b * 2048 + qt * 256 + wave * 64);
#pragma unroll
  for (int r = 0; r < 16; ++r) {
    const int qr = (r & 3) + 8 * (r >> 2) + 4 * hi;   // C/D row map
    const float dA = __shfl(ivA, qr);
    const float dB = __shfl(ivB, qr);
#pragma unroll
    for (int nd = 0; nd < 2; ++nd) {
      const int dk = nd * 32 + l31;
      ctx[(rowbase + qr) * 1024 + h * 64 + dk]      = (bf16)(oA[nd][r] * dA);
      ctx[(rowbase + 32 + qr) * 1024 + h * 64 + dk] = (bf16)(oB[nd][r] * dB);
    }
  }
}

// ------------- residual + layernorm: out = LN(resid + delta)*g + b -------------
template <typename RT, typename DT, typename OT>
__global__ void __launch_bounds__(256)
k_ln(const RT* __restrict__ resid, const DT* __restrict__ delta,
     const float* __restrict__ g, const float* __restrict__ bta,
     OT* __restrict__ out) {
  const int row = blockIdx.x, tid = threadIdx.x;
  const int wave = tid >> 6, lane = tid & 63;
  __shared__ float rs_[4], rs2_[4];
  const RT* r = resid + (size_t)row * 1024;
  const DT* d = delta + (size_t)row * 1024;
  OT* o = out + (size_t)row * 1024;
  float x[4], s = 0.f, s2 = 0.f;
#pragma unroll
  for (int j = 0; j < 4; ++j) {
    int idx = tid + j * 256;
    float v = (float)r[idx] + (float)d[idx];
    x[j] = v; s += v; s2 += v * v;
  }
#pragma unroll
  for (int m = 32; m >= 1; m >>= 1) { s += __shfl_xor(s, m); s2 += __shfl_xor(s2, m); }
  if (lane == 0) { rs_[wave] = s; rs2_[wave] = s2; }
  __syncthreads();
  float ts = rs_[0] + rs_[1] + rs_[2] + rs_[3];
  float ts2 = rs2_[0] + rs2_[1] + rs2_[2] + rs2_[3];
  float mean = ts * (1.f / 1024.f);
  float var = ts2 * (1.f / 1024.f) - mean * mean;
  float rstd = rsqrtf(var + 1e-5f);
#pragma unroll
  for (int j = 0; j < 4; ++j) {
    int idx = tid + j * 256;
    o[idx] = (OT)((x[j] - mean) * rstd * g[idx] + bta[idx]);
  }
}

// ---------------- launch ----------------
extern "C" void kernel_launch(void* const* d_in, const int* in_sizes, int n_in,
                              void* d_out, int out_size, void* d_ws, size_t ws_size,
                              hipStream_t stream) {
  const float* src  = (const float*)d_in[0];
  const float* Wq   = (const float*)d_in[1];
  const float* bq   = (const float*)d_in[2];
  const float* Wk   = (const float*)d_in[3];
  const float* bk   = (const float*)d_in[4];
  const float* Wv   = (const float*)d_in[5];
  const float* bv   = (const float*)d_in[6];
  const float* Wo   = (const float*)d_in[7];
  const float* bo   = (const float*)d_in[8];
  const float* ln1g = (const float*)d_in[9];
  const float* ln1b = (const float*)d_in[10];
  const float* W1   = (const float*)d_in[11];
  const float* b1   = (const float*)d_in[12];
  const float* W2   = (const float*)d_in[13];
  const float* b2   = (const float*)d_in[14];
  const float* ln2g = (const float*)d_in[15];
  const float* ln2b = (const float*)d_in[16];

  char* p = (char*)d_ws;
  bf16*  WqkvT = (bf16*)p;  p += (size_t)3072 * 1024 * 2;
  float* bqkv  = (float*)p; p += 16384;
  bf16*  WoT   = (bf16*)p;  p += (size_t)1024 * 1024 * 2;
  bf16*  W1T   = (bf16*)p;  p += (size_t)4096 * 1024 * 2;
  bf16*  W2T   = (bf16*)p;  p += (size_t)1024 * 4096 * 2;
  bf16*  srcb  = (bf16*)p;  p += (size_t)8388608 * 2;
  bf16*  qbuf  = (bf16*)p;  p += (size_t)8388608 * 2;
  bf16*  kbuf  = (bf16*)p;  p += (size_t)8388608 * 2;
  bf16*  vbuf  = (bf16*)p;  p += (size_t)8388608 * 2;   // V^T (b,h,dk,s)
  bf16*  ctx   = (bf16*)p;  p += (size_t)8388608 * 2;
  bf16*  x1    = (bf16*)p;  p += (size_t)8388608 * 2;
  bf16*  ff1   = (bf16*)p;  p += (size_t)8192 * 4096 * 2;
  bf16*  tmp   = qbuf;   // bf16 GEMM out; aliases qbuf (dead after attention)

  k_cast<<<4096, 256, 0, stream>>>(src, srcb);
  k_reorder_qkv_t<<<768, 256, 0, stream>>>(Wq, Wk, Wv, WqkvT);
  k_bias_qkv<<<12, 256, 0, stream>>>(bq, bk, bv, bqkv);
  k_transpose_t<<<256, 256, 0, stream>>>(Wo, WoT, 1024, 1024);
  k_transpose_t<<<1024, 256, 0, stream>>>(W1, W1T, 1024, 4096);
  k_transpose_t<<<1024, 256, 0, stream>>>(W2, W2T, 4096, 1024);

  // QKV projection: (8192x1024) @ (1024x3072), 128x256 tiles -> grid 768
  k_gemmS<0><<<768, 512, 0, stream>>>(srcb, WqkvT, bqkv, nullptr,
                                      8192, 3072, 1024, qbuf, kbuf, vbuf);
  // attention -> ctx (B,S,H*DK)
  k_attn<<<512, 256, 0, stream>>>(qbuf, kbuf, vbuf, ctx);
  // out projection -> tmp (bf16), 128x256 tiles -> grid 256
  k_gemmS<1><<<256, 512, 0, stream>>>(ctx, WoT, bo, tmp,
                                      8192, 1024, 1024, nullptr, nullptr, nullptr);
  // x1 = LN(src + tmp)
  k_ln<float, bf16, bf16><<<8192, 256, 0, stream>>>(src, tmp, ln1g, ln1b, x1);
  // ff1 = relu(x1 @ W1 + b1), 256x256 tiles -> grid 512
  k_gemm4<2, 2><<<512, 512, 0, stream>>>(x1, W1T, b1, ff1,
                                         8192, 4096, 1024, nullptr, nullptr, nullptr);
  // tmp = ff1 @ W2 + b2, 128x256 tiles -> grid 256
  k_gemmS<1><<<256, 512, 0, stream>>>(ff1, W2T, b2, tmp,
                                      8192, 1024, 4096, nullptr, nullptr, nullptr);
  // out = LN(x1 + tmp) -> f32
  k_ln<bf16, bf16, float><<<8192, 256, 0, stream>>>(x1, tmp, ln2g, ln2b, (float*)d_out);
}

// Round 6
// 482.165 us; speedup vs baseline: 1.0466x; 1.0466x over previous
//
#include <hip/hip_runtime.h>
#include <hip/hip_bf16.h>
#include <cstddef>
#include <cstdint>

typedef __bf16 bf16;
typedef __bf16 bf16x4 __attribute__((ext_vector_type(4)));
typedef __bf16 bf16x8 __attribute__((ext_vector_type(8)));
typedef float f32x4 __attribute__((ext_vector_type(4)));
typedef float f32x16 __attribute__((ext_vector_type(16)));
typedef unsigned int u32x4 __attribute__((ext_vector_type(4)));

#define GLD_LDS16(g, l) __builtin_amdgcn_global_load_lds( \
    (const __attribute__((address_space(1))) void*)(g),   \
    (__attribute__((address_space(3))) void*)(l), 16, 0, 0)

#define SBAR __builtin_amdgcn_s_barrier()
#define SCHED0 __builtin_amdgcn_sched_barrier(0)
#define VMW(n) asm volatile("s_waitcnt vmcnt(" #n ")" ::: "memory")

// pack two f32 -> one u32 of 2 bf16 (elem0 = lo, elem1 = hi)
static __device__ inline unsigned int cvtpk(float lo, float hi) {
  unsigned int r;
  asm("v_cvt_pk_bf16_f32 %0, %1, %2" : "=v"(r) : "v"(lo), "v"(hi));
  return r;
}
// v_permlane32_swap_b32: a.hi32lanes <-> b.lo32lanes
static __device__ inline void plswap(unsigned int& a, unsigned int& b) {
  asm("v_permlane32_swap_b32 %0, %1" : "+v"(a), "+v"(b));
}
// raw hardware exp2 (inputs bounded; no denormal guard needed)
static __device__ inline float fexp2(float x) {
#if __has_builtin(__builtin_amdgcn_exp2f)
  return __builtin_amdgcn_exp2f(x);
#else
  float r; asm("v_exp_f32 %0, %1" : "=v"(r) : "v"(x)); return r;
#endif
}
// pairwise tree sum of 16 floats (depth 4, no serial chain)
static __device__ inline float tsum16(const float* e) {
  float s0 = e[0] + e[1], s1 = e[2] + e[3], s2 = e[4] + e[5], s3 = e[6] + e[7];
  float s4 = e[8] + e[9], s5 = e[10] + e[11], s6 = e[12] + e[13], s7 = e[14] + e[15];
  return ((s0 + s1) + (s2 + s3)) + ((s4 + s5) + (s6 + s7));
}

// ---------------- src cast: f32 -> bf16, 8 elems/thread ----------------
__global__ void __launch_bounds__(256)
k_cast(const float* __restrict__ in, bf16* __restrict__ out) {
  int gid = blockIdx.x * 256 + threadIdx.x;
  f32x4 a = ((const f32x4*)in)[gid * 2];
  f32x4 b = ((const f32x4*)in)[gid * 2 + 1];
  bf16x8 o;
#pragma unroll
  for (int i = 0; i < 4; ++i) { o[i] = (bf16)a[i]; o[i + 4] = (bf16)b[i]; }
  ((bf16x8*)out)[gid] = o;
}

// ---- tiled transpose: in f32 (R x C) -> out bf16 (C x R), 64x64 tiles ----
__global__ void __launch_bounds__(256)
k_transpose_t(const float* __restrict__ in, bf16* __restrict__ out, int R, int C) {
  __shared__ float tile[64][68];
  const int nct = C >> 6;
  const int bc = blockIdx.x % nct, br = blockIdx.x / nct;
  const int r0 = br << 6, c0 = bc << 6;
  const int t = threadIdx.x;
  const int tr = t >> 4, tc4 = (t & 15) << 2;
#pragma unroll
  for (int i = 0; i < 4; ++i)
    *(f32x4*)&tile[i * 16 + tr][tc4] =
        *(const f32x4*)&in[(size_t)(r0 + i * 16 + tr) * C + c0 + tc4];
  __syncthreads();
  const int c = t >> 2, rch = (t & 3) << 4;
  bf16 ob[16];
#pragma unroll
  for (int j = 0; j < 16; ++j) ob[j] = (bf16)tile[rch + j][c];
  bf16* dst = out + (size_t)(c0 + c) * R + r0 + rch;
  *(bf16x8*)&dst[0] = *(bf16x8*)&ob[0];
  *(bf16x8*)&dst[8] = *(bf16x8*)&ob[8];
}

// ---- QKV weight repack (tiled): W (H,D,DK) f32 -> WqkvT[(proj*1024+h*64+dk)][d] bf16 ----
__global__ void __launch_bounds__(256)
k_reorder_qkv_t(const float* __restrict__ Wq, const float* __restrict__ Wk,
                const float* __restrict__ Wv, bf16* __restrict__ WqkvT) {
  __shared__ float tile[64][68];
  const int bid = blockIdx.x;
  const int sub = bid >> 4, tl = bid & 15;
  const int proj = sub >> 4, h = sub & 15;
  const float* W = (proj == 0) ? Wq : (proj == 1) ? Wk : Wv;
  const float* src = W + (size_t)h * 65536;   // (1024 d x 64 dk)
  const int r0 = tl << 6;
  const int t = threadIdx.x, tr = t >> 4, tc4 = (t & 15) << 2;
#pragma unroll
  for (int i = 0; i < 4; ++i)
    *(f32x4*)&tile[i * 16 + tr][tc4] =
        *(const f32x4*)&src[(size_t)(r0 + i * 16 + tr) * 64 + tc4];
  __syncthreads();
  const int c = t >> 2, rch = (t & 3) << 4;   // c = dk
  bf16 ob[16];
#pragma unroll
  for (int j = 0; j < 16; ++j) ob[j] = (bf16)tile[rch + j][c];
  bf16* dst = WqkvT + ((size_t)(proj * 1024 + h * 64 + c)) * 1024 + r0 + rch;
  *(bf16x8*)&dst[0] = *(bf16x8*)&ob[0];
  *(bf16x8*)&dst[8] = *(bf16x8*)&ob[8];
}

__global__ void __launch_bounds__(256)
k_bias_qkv(const float* __restrict__ bq, const float* __restrict__ bk,
           const float* __restrict__ bv, float* __restrict__ bqkv) {
  int n = blockIdx.x * 256 + threadIdx.x;   // 3072
  int proj = n >> 10, wi = n & 1023;
  const float* bb = (proj == 0) ? bq : (proj == 1) ? bk : bv;
  bqkv[n] = bb[wi];
}

// ======== 4-fat-phase 256xBN GEMM: C = A(MxK) @ Bt(NxK)^T + bias ========
// 512 thr / 8 waves (2M x 4N). BK=64, K-tiles in pairs, 4 phases/iter,
// 16*NREP MFMA per phase. Linear wg mapping (tile_m fastest).
// THINNED counted-vmcnt: waits only at pe2/po2 (covering-wait proof:
// pe2 allows its own 3/4 outstanding; po2 its own 4/6; prologue 4/6).
// MODE 0: QKV scatter; 1: bf16 out; 2: relu bf16 out; 3: f32 split-K partial.
// splitk: grid = tiles*splitk; block s handles k in [s*klen, s*klen+klen).
template <int MODE, int NREP>
__global__ void __launch_bounds__(512, 1)
k_gemm4(const bf16* __restrict__ A, const bf16* __restrict__ Bt,
        const float* __restrict__ bias, void* __restrict__ outp,
        int M, int N, int K, int klen, int splitk,
        bf16* __restrict__ qb, bf16* __restrict__ kb, bf16* __restrict__ vb) {
  constexpr int BN = 128 * NREP;
  constexpr int BROWS = 64 * NREP;          // rows per B half-slot
  __shared__ __align__(16) bf16 Asl[4][8192];          // 4 x (128 x 64)
  __shared__ __align__(16) bf16 Bsl[4][BROWS * 64];    // 4 x (BROWS x 64)

  const int tid = threadIdx.x;
  const int lane = tid & 63, wave = tid >> 6;
  const int l16 = lane & 15, lq = lane >> 4;
  const int qwm = wave >> 2, qwn = wave & 3;

  const int tiles = gridDim.x / splitk;
  const int twg = blockIdx.x % tiles;
  const int sk = blockIdx.x / tiles;
  const int k0 = sk * klen;
  const int mtiles = M >> 8;
  const int tile_m = (twg % mtiles) << 8;
  const int tile_n = (twg / mtiles) * BN;

  const bf16* Abase = A + (size_t)tile_m * K + k0;
  const bf16* Bbase = Bt + (size_t)tile_n * K + k0;

  const int crow = tid >> 3;
  const int ccol = ((tid & 7) ^ (crow & 7)) << 3;

  auto stageA = [&](int T, int h, int slot) {
    const bf16* s_ = Abase + (size_t)(h * 128 + crow) * K + T * 64 + ccol;
    GLD_LDS16(s_, &Asl[slot][tid * 8]);
    GLD_LDS16(s_ + (size_t)64 * K, &Asl[slot][tid * 8 + 4096]);
  };
  auto stageB = [&](int T, int h, int slot) {
    const bf16* s_ = Bbase + (size_t)(h * BROWS + crow) * K + T * 64 + ccol;
    GLD_LDS16(s_, &Bsl[slot][tid * 8]);
    if (NREP == 2) GLD_LDS16(s_ + (size_t)64 * K, &Bsl[slot][tid * 8 + 4096]);
  };

  const int xk = l16 & 7;
  const int swz0 = (lq ^ xk) * 16;
  const int swz1 = ((4 | lq) ^ xk) * 16;
  const int arow_b = (qwm * 64 + l16) * 128;
  const int brow_b = (qwn * 16 * NREP + l16) * 128;

  bf16x8 af[4][2];
  bf16x8 bb[2][NREP][2];
  f32x4 acc[2][2][4][NREP] = {};

  auto dsA = [&](int slot) {
    const char* Ab = (const char*)&Asl[slot][0] + arow_b;
#pragma unroll
    for (int mi = 0; mi < 4; ++mi) {
      af[mi][0] = *(const bf16x8*)(Ab + mi * 2048 + swz0);
      af[mi][1] = *(const bf16x8*)(Ab + mi * 2048 + swz1);
    }
  };
  auto dsB2 = [&](int slot0, int slot1) {
    const char* B0 = (const char*)&Bsl[slot0][0] + brow_b;
    const char* B1 = (const char*)&Bsl[slot1][0] + brow_b;
#pragma unroll
    for (int ni = 0; ni < NREP; ++ni) {
      bb[0][ni][0] = *(const bf16x8*)(B0 + ni * 2048 + swz0);
      bb[0][ni][1] = *(const bf16x8*)(B0 + ni * 2048 + swz1);
      bb[1][ni][0] = *(const bf16x8*)(B1 + ni * 2048 + swz0);
      bb[1][ni][1] = *(const bf16x8*)(B1 + ni * 2048 + swz1);
    }
  };
  auto MF2 = [&](int mh) {
    __builtin_amdgcn_s_setprio(1);
#pragma unroll
    for (int nh = 0; nh < 2; ++nh)
#pragma unroll
      for (int mi = 0; mi < 4; ++mi)
#pragma unroll
        for (int ni = 0; ni < NREP; ++ni)
#pragma unroll
          for (int p = 0; p < 2; ++p)
            acc[mh][nh][mi][ni] = __builtin_amdgcn_mfma_f32_16x16x32_bf16(
                af[mi][p], bb[nh][ni][p], acc[mh][nh][mi][ni], 0, 0, 0);
    __builtin_amdgcn_s_setprio(0);
  };

  const int NT = klen >> 6;
  const int NI = NT >> 1;

  // prologue: A0 A1 B0 B1 A2 B2 B3 ; wait leaves last 3 calls outstanding
  stageA(0, 0, 0); stageA(0, 1, 1); stageB(0, 0, 0); stageB(0, 1, 1);
  stageA(1, 0, 2); stageB(1, 0, 2); stageB(1, 1, 3);
  SCHED0;
  if (NREP == 2) { VMW(6); } else { VMW(4); }
  SBAR;

  for (int i = 0; i < NI; ++i) {
    const int t2 = 2 * i + 2, t3 = 2 * i + 3;
    const bool tv = (t2 < NT);
    // pe1: even tile, A-half0 x both B  (no wait: covered by prev po2)
    dsA(0); dsB2(0, 1);
    stageA(2 * i + 1, 1, 3);
    SBAR; MF2(0); SBAR;
    // pe2: even tile, A-half1 ; wait covers po1/po2 reads
    dsA(1);
    if (tv) { stageA(t2, 0, 0); stageB(t2, 0, 0); }
    SCHED0;
    if (!tv) { VMW(0); }
    else if (NREP == 2) { VMW(4); } else { VMW(3); }
    SBAR; MF2(1); SBAR;
    // po1: odd tile, A-half0 x both B  (no wait)
    dsA(2); dsB2(2, 3);
    if (tv) { stageA(t2, 1, 1); stageB(t2, 1, 1); }
    SBAR; MF2(0); SBAR;
    // po2: odd tile, A-half1 ; wait covers next pe1/pe2 reads
    dsA(3);
    if (tv) {
      stageA(t3, 0, 2); stageB(t3, 0, 2); stageB(t3, 1, 3);
      SCHED0;
      if (NREP == 2) { VMW(6); } else { VMW(4); }
    }
    SBAR; MF2(1); SBAR;
  }

  // ---------------- epilogue ----------------
  float* psplit = (MODE == 3) ? ((float*)outp + (size_t)sk * M * N) : nullptr;
#pragma unroll
  for (int mh = 0; mh < 2; ++mh)
#pragma unroll
    for (int nh = 0; nh < 2; ++nh)
#pragma unroll
      for (int mi = 0; mi < 4; ++mi)
#pragma unroll
        for (int ni = 0; ni < NREP; ++ni) {
          const int gn = tile_n + nh * (BN / 2) + qwn * 16 * NREP + ni * 16 + l16;
          const float bv = (MODE == 3) ? 0.f : bias[gn];
          f32x4 v = acc[mh][nh][mi][ni];
          const int gm0 = tile_m + mh * 128 + qwm * 64 + mi * 16 + lq * 4;
          if (MODE == 0) {
            int proj = gn >> 10, wi = gn & 1023;
            int h = wi >> 6, dk = wi & 63;
            int b = gm0 >> 11, sdx = gm0 & 2047;
            size_t bhs = (size_t)((b << 4) + h);
            if (proj == 0) {
#pragma unroll
              for (int i2 = 0; i2 < 4; ++i2)
                qb[(bhs * 2048 + sdx + i2) * 64 + dk] = (bf16)((v[i2] + bv) * 0.18033688f);
            } else if (proj == 1) {
#pragma unroll
              for (int i2 = 0; i2 < 4; ++i2)
                kb[(bhs * 2048 + sdx + i2) * 64 + dk] = (bf16)(v[i2] + bv);
            } else {
              bf16x4 pk;
#pragma unroll
              for (int i2 = 0; i2 < 4; ++i2) pk[i2] = (bf16)(v[i2] + bv);
              *(bf16x4*)&vb[(bhs * 64 + dk) * 2048 + sdx] = pk;   // V^T
            }
          } else if (MODE == 1) {
#pragma unroll
            for (int i2 = 0; i2 < 4; ++i2)
              ((bf16*)outp)[(size_t)(gm0 + i2) * N + gn] = (bf16)(v[i2] + bv);
          } else if (MODE == 2) {
#pragma unroll
            for (int i2 = 0; i2 < 4; ++i2)
              ((bf16*)outp)[(size_t)(gm0 + i2) * N + gn] = (bf16)fmaxf(v[i2] + bv, 0.f);
          } else {
#pragma unroll
            for (int i2 = 0; i2 < 4; ++i2)
              psplit[(size_t)(gm0 + i2) * N + gn] = v[i2];
          }
        }
}

// ---- flash attention, 32x32 MFMA, triple-buffered counted-vmcnt pipeline ----
__global__ void __launch_bounds__(256, 2)
k_attn(const bf16* __restrict__ qb, const bf16* __restrict__ kb,
       const bf16* __restrict__ vb, bf16* __restrict__ ctx) {
  __shared__ __align__(16) bf16 KsL[3][4096];   // [64 s][64 d], swizzled chunks
  __shared__ __align__(16) bf16 VsL[3][4096];   // [64 d][64 s], swizzled chunks

  const int bid = blockIdx.x;
  const int wg = (bid & 7) * 64 + (bid >> 3);
  const int bh = wg >> 3, qt = wg & 7;

  const bf16* Qp  = qb + (size_t)bh * 131072 + (size_t)qt * 16384;
  const bf16* Kbh = kb + (size_t)bh * 131072;
  const bf16* Vbh = vb + (size_t)bh * 131072;

  const int tid = threadIdx.x, wave = tid >> 6, lane = tid & 63;
  const int l31 = lane & 31, hi = lane >> 5;

  bf16x8 qfA[4], qfB[4];
  {
    const bf16* qra = Qp + (size_t)(wave * 64 + l31) * 64 + hi * 8;
    const bf16* qrb = qra + 32 * 64;
#pragma unroll
    for (int kd = 0; kd < 4; ++kd) {
      qfA[kd] = *(const bf16x8*)(qra + kd * 16);
      qfB[kd] = *(const bf16x8*)(qrb + kd * 16);
    }
  }

  const int c0 = tid, c1 = tid + 256;
  const int sw0 = ((c0 ^ (c0 >> 3)) & 7) * 8, rw0 = c0 >> 3;
  const int sw1 = ((c1 ^ (c1 >> 3)) & 7) * 8, rw1 = c1 >> 3;
  const int kof0 = rw0 * 64 + sw0, kof1 = rw1 * 64 + sw1;
  const int vof0 = rw0 * 2048 + sw0, vof1 = rw1 * 2048 + sw1;

  const int xr = (hi << 4) ^ ((l31 & 7) << 4);
  const int rb = l31 * 128 + xr;

  f32x16 oA[2] = {}, oB[2] = {};
  float lA = 0.f, lB = 0.f;

#define STAGE_KV(buf, s0)                                             \
  do {                                                                \
    GLD_LDS16(Kbh + (size_t)(s0) * 64 + kof0, &KsL[buf][c0 * 8]);     \
    GLD_LDS16(Kbh + (size_t)(s0) * 64 + kof1, &KsL[buf][c1 * 8]);     \
    GLD_LDS16(Vbh + (s0) + vof0, &VsL[buf][c0 * 8]);                  \
    GLD_LDS16(Vbh + (s0) + vof1, &VsL[buf][c1 * 8]);                  \
  } while (0)

  STAGE_KV(0, 0);
  STAGE_KV(1, 64);

  int cur = 0;
  for (int kt = 0; kt < 32; ++kt) {
    SCHED0;
    if (kt == 31) { VMW(0); }
    else          { VMW(4); }
    __builtin_amdgcn_s_barrier();
    SCHED0;

    if (kt < 30) {
      int nx = cur + 2; if (nx >= 3) nx -= 3;
      STAGE_KV(nx, (kt + 2) * 64);
    }

    const char* Kc = (const char*)&KsL[cur][0];
    const char* Vc = (const char*)&VsL[cur][0];

    bf16x8 paA[4], paB[4];
#pragma unroll
    for (int st = 0; st < 2; ++st) {
      f32x16 sA = {}, sB = {};
      __builtin_amdgcn_s_setprio(1);
#pragma unroll
      for (int kd = 0; kd < 4; ++kd) {
        bf16x8 a = *(const bf16x8*)(Kc + st * 4096 + (rb ^ (kd << 5)));
        sA = __builtin_amdgcn_mfma_f32_32x32x16_bf16(a, qfA[kd], sA, 0, 0, 0);
        sB = __builtin_amdgcn_mfma_f32_32x32x16_bf16(a, qfB[kd], sB, 0, 0, 0);
      }
      __builtin_amdgcn_s_setprio(0);

      float eA[16], eB[16];
#pragma unroll
      for (int i = 0; i < 16; ++i) {
        eA[i] = fexp2(sA[i]);
        eB[i] = fexp2(sB[i]);
      }
      lA += tsum16(eA);
      lB += tsum16(eB);
      unsigned int qdA[4][2], qdB[4][2];
#pragma unroll
      for (int g = 0; g < 4; ++g)
#pragma unroll
        for (int w = 0; w < 2; ++w) {
          qdA[g][w] = cvtpk(eA[g * 4 + w * 2], eA[g * 4 + w * 2 + 1]);
          qdB[g][w] = cvtpk(eB[g * 4 + w * 2], eB[g * 4 + w * 2 + 1]);
        }
#pragma unroll
      for (int a2 = 0; a2 < 2; ++a2) {
        unsigned int x0 = qdA[2 * a2][0], y0 = qdA[2 * a2 + 1][0];
        unsigned int x1 = qdA[2 * a2][1], y1 = qdA[2 * a2 + 1][1];
        plswap(x0, y0); plswap(x1, y1);
        u32x4 fA = {x0, x1, y0, y1};
        paA[st * 2 + a2] = __builtin_bit_cast(bf16x8, fA);
        unsigned int u0 = qdB[2 * a2][0], v0 = qdB[2 * a2 + 1][0];
        unsigned int u1 = qdB[2 * a2][1], v1 = qdB[2 * a2 + 1][1];
        plswap(u0, v0); plswap(u1, v1);
        u32x4 fB = {u0, u1, v0, v1};
        paB[st * 2 + a2] = __builtin_bit_cast(bf16x8, fB);
      }
    }

    __builtin_amdgcn_s_setprio(1);
#pragma unroll
    for (int nd = 0; nd < 2; ++nd)
#pragma unroll
      for (int ks = 0; ks < 4; ++ks) {
        bf16x8 vf = *(const bf16x8*)(Vc + nd * 4096 + (rb ^ (ks << 5)));
        oA[nd] = __builtin_amdgcn_mfma_f32_32x32x16_bf16(paA[ks], vf, oA[nd], 0, 0, 0);
        oB[nd] = __builtin_amdgcn_mfma_f32_32x32x16_bf16(paB[ks], vf, oB[nd], 0, 0, 0);
      }
    __builtin_amdgcn_s_setprio(0);

    if (++cur == 3) cur = 0;
  }
#undef STAGE_KV

  const float ltA = lA + __shfl_xor(lA, 32);
  const float ltB = lB + __shfl_xor(lB, 32);
  const float ivA = 1.f / ltA;
  const float ivB = 1.f / ltB;

  const int b = bh >> 4, h = bh & 15;
  const size_t rowbase = (size_t)(b * 2048 + qt * 256 + wave * 64);
#pragma unroll
  for (int r = 0; r < 16; ++r) {
    const int qr = (r & 3) + 8 * (r >> 2) + 4 * hi;   // C/D row map
    const float dA = __shfl(ivA, qr);
    const float dB = __shfl(ivB, qr);
#pragma unroll
    for (int nd = 0; nd < 2; ++nd) {
      const int dk = nd * 32 + l31;
      ctx[(rowbase + qr) * 1024 + h * 64 + dk]      = (bf16)(oA[nd][r] * dA);
      ctx[(rowbase + 32 + qr) * 1024 + h * 64 + dk] = (bf16)(oB[nd][r] * dB);
    }
  }
}

// ------------- residual + layernorm: out = LN(resid + delta)*g + b -------------
template <typename RT, typename DT, typename OT>
__global__ void __launch_bounds__(256)
k_ln(const RT* __restrict__ resid, const DT* __restrict__ delta,
     const float* __restrict__ g, const float* __restrict__ bta,
     OT* __restrict__ out) {
  const int row = blockIdx.x, tid = threadIdx.x;
  const int wave = tid >> 6, lane = tid & 63;
  __shared__ float rs_[4], rs2_[4];
  const RT* r = resid + (size_t)row * 1024;
  const DT* d = delta + (size_t)row * 1024;
  OT* o = out + (size_t)row * 1024;
  float x[4], s = 0.f, s2 = 0.f;
#pragma unroll
  for (int j = 0; j < 4; ++j) {
    int idx = tid + j * 256;
    float v = (float)r[idx] + (float)d[idx];
    x[j] = v; s += v; s2 += v * v;
  }
#pragma unroll
  for (int m = 32; m >= 1; m >>= 1) { s += __shfl_xor(s, m); s2 += __shfl_xor(s2, m); }
  if (lane == 0) { rs_[wave] = s; rs2_[wave] = s2; }
  __syncthreads();
  float ts = rs_[0] + rs_[1] + rs_[2] + rs_[3];
  float ts2 = rs2_[0] + rs2_[1] + rs2_[2] + rs2_[3];
  float mean = ts * (1.f / 1024.f);
  float var = ts2 * (1.f / 1024.f) - mean * mean;
  float rstd = rsqrtf(var + 1e-5f);
#pragma unroll
  for (int j = 0; j < 4; ++j) {
    int idx = tid + j * 256;
    o[idx] = (OT)((x[j] - mean) * rstd * g[idx] + bta[idx]);
  }
}

// ---- split-K LN: out = LN(x1 + p0 + p1 + bias)*g + b, f32 out ----
__global__ void __launch_bounds__(256)
k_ln_sk(const bf16* __restrict__ x1r, const float* __restrict__ p0,
        const float* __restrict__ p1, const float* __restrict__ bias,
        const float* __restrict__ g, const float* __restrict__ bta,
        float* __restrict__ out) {
  const int row = blockIdx.x, tid = threadIdx.x;
  const int wave = tid >> 6, lane = tid & 63;
  __shared__ float rs_[4], rs2_[4];
  const bf16* r = x1r + (size_t)row * 1024;
  const float* a = p0 + (size_t)row * 1024;
  const float* b = p1 + (size_t)row * 1024;
  float* o = out + (size_t)row * 1024;
  float x[4], s = 0.f, s2 = 0.f;
#pragma unroll
  for (int j = 0; j < 4; ++j) {
    int idx = tid + j * 256;
    float v = (float)r[idx] + a[idx] + b[idx] + bias[idx];
    x[j] = v; s += v; s2 += v * v;
  }
#pragma unroll
  for (int m = 32; m >= 1; m >>= 1) { s += __shfl_xor(s, m); s2 += __shfl_xor(s2, m); }
  if (lane == 0) { rs_[wave] = s; rs2_[wave] = s2; }
  __syncthreads();
  float ts = rs_[0] + rs_[1] + rs_[2] + rs_[3];
  float ts2 = rs2_[0] + rs2_[1] + rs2_[2] + rs2_[3];
  float mean = ts * (1.f / 1024.f);
  float var = ts2 * (1.f / 1024.f) - mean * mean;
  float rstd = rsqrtf(var + 1e-5f);
#pragma unroll
  for (int j = 0; j < 4; ++j) {
    int idx = tid + j * 256;
    o[idx] = (x[j] - mean) * rstd * g[idx] + bta[idx];
  }
}

// ---------------- launch ----------------
extern "C" void kernel_launch(void* const* d_in, const int* in_sizes, int n_in,
                              void* d_out, int out_size, void* d_ws, size_t ws_size,
                              hipStream_t stream) {
  const float* src  = (const float*)d_in[0];
  const float* Wq   = (const float*)d_in[1];
  const float* bq   = (const float*)d_in[2];
  const float* Wk   = (const float*)d_in[3];
  const float* bk   = (const float*)d_in[4];
  const float* Wv   = (const float*)d_in[5];
  const float* bv   = (const float*)d_in[6];
  const float* Wo   = (const float*)d_in[7];
  const float* bo   = (const float*)d_in[8];
  const float* ln1g = (const float*)d_in[9];
  const float* ln1b = (const float*)d_in[10];
  const float* W1   = (const float*)d_in[11];
  const float* b1   = (const float*)d_in[12];
  const float* W2   = (const float*)d_in[13];
  const float* b2   = (const float*)d_in[14];
  const float* ln2g = (const float*)d_in[15];
  const float* ln2b = (const float*)d_in[16];

  char* p = (char*)d_ws;
  bf16*  WqkvT = (bf16*)p;  p += (size_t)3072 * 1024 * 2;
  float* bqkv  = (float*)p; p += 16384;
  bf16*  WoT   = (bf16*)p;  p += (size_t)1024 * 1024 * 2;
  bf16*  W1T   = (bf16*)p;  p += (size_t)4096 * 1024 * 2;
  bf16*  W2T   = (bf16*)p;  p += (size_t)1024 * 4096 * 2;
  bf16*  srcb  = (bf16*)p;  p += (size_t)8388608 * 2;
  bf16*  qbuf  = (bf16*)p;  p += (size_t)8388608 * 2;
  bf16*  kbuf  = (bf16*)p;  p += (size_t)8388608 * 2;
  bf16*  vbuf  = (bf16*)p;  p += (size_t)8388608 * 2;   // V^T (b,h,dk,s)
  bf16*  ctx   = (bf16*)p;  p += (size_t)8388608 * 2;
  bf16*  x1    = (bf16*)p;  p += (size_t)8388608 * 2;
  bf16*  ff1   = (bf16*)p;  p += (size_t)8192 * 4096 * 2;
  bf16*  tmp   = qbuf;   // bf16 GEMM out; aliases qbuf (dead after attention)
  // split-K f32 partials: overlay dead srcb..vbuf region (67.1MB fits exactly)
  float* pk0   = (float*)srcb;

  k_cast<<<4096, 256, 0, stream>>>(src, srcb);
  k_reorder_qkv_t<<<768, 256, 0, stream>>>(Wq, Wk, Wv, WqkvT);
  k_bias_qkv<<<12, 256, 0, stream>>>(bq, bk, bv, bqkv);
  k_transpose_t<<<256, 256, 0, stream>>>(Wo, WoT, 1024, 1024);
  k_transpose_t<<<1024, 256, 0, stream>>>(W1, W1T, 1024, 4096);
  k_transpose_t<<<1024, 256, 0, stream>>>(W2, W2T, 4096, 1024);

  // QKV projection: (8192x1024) @ (1024x3072), BN=128 -> grid 768
  k_gemm4<0, 1><<<768, 512, 0, stream>>>(srcb, WqkvT, bqkv, nullptr,
                                         8192, 3072, 1024, 1024, 1, qbuf, kbuf, vbuf);
  // attention -> ctx (B,S,H*DK)
  k_attn<<<512, 256, 0, stream>>>(qbuf, kbuf, vbuf, ctx);
  // out projection -> tmp (bf16), BN=128 -> grid 256
  k_gemm4<1, 1><<<256, 512, 0, stream>>>(ctx, WoT, bo, tmp,
                                         8192, 1024, 1024, 1024, 1, nullptr, nullptr, nullptr);
  // x1 = LN(src + tmp)
  k_ln<float, bf16, bf16><<<8192, 256, 0, stream>>>(src, tmp, ln1g, ln1b, x1);
  // ff1 = relu(x1 @ W1 + b1), BN=256 -> grid 512
  k_gemm4<2, 2><<<512, 512, 0, stream>>>(x1, W1T, b1, ff1,
                                         8192, 4096, 1024, 1024, 1, nullptr, nullptr, nullptr);
  // FF2 split-K=2: 256x256 tiles, grid 128*2, f32 partials pk0/pk1
  k_gemm4<3, 2><<<256, 512, 0, stream>>>(ff1, W2T, nullptr, pk0,
                                         8192, 1024, 4096, 2048, 2, nullptr, nullptr, nullptr);
  // out = LN(x1 + pk0 + pk1 + b2) -> f32
  k_ln_sk<<<8192, 256, 0, stream>>>(x1, pk0, pk0 + (size_t)8192 * 1024, b2,
                                    ln2g, ln2b, (float*)d_out);
}